// Round 5
// baseline (344.584 us; speedup 1.0000x reference)
//
#include <hip/hip_runtime.h>
#include <hip/hip_bf16.h>
#include <cstdint>

typedef unsigned short ushortT;
typedef __attribute__((ext_vector_type(8))) short short8;
typedef __attribute__((ext_vector_type(4))) float f32x4;

// ---------------- problem constants ----------------
static constexpr int Bn = 4, Cc = 48, Hh = 64, Wd = 64, HW = 4096;
static constexpr int HID = 96, NSET = 32, INTERC = 24, HEADS = 8, CPH = 6;

// ---------------- ws layout (float offsets) ----------------
static constexpr int FXN   = 0;         // 786432  xn ; later mdta
static constexpr int FA    = 786432;    // 1572864 t1 -> hbuf -> qkvr(lo) -> Sp
static constexpr int FB    = 2359296;   // 1572864 t2 -> qkvr(hi)
static constexpr int FC    = 3932160;   // 1572864 x1g -> qkv(lo)
static constexpr int FD    = 5505024;   // 1572864 uf -> qkv(hi)
static constexpr int FATT  = 7471104;   // 524288  attn_t fp32 [p][n]
static constexpr int FKBA  = 7995392;   // 786432
static constexpr int FGAP  = 8781824;   // 192
static constexpr int FCA1  = 8782016;   // 192
static constexpr int FCA2  = 8782208;   // 192
static constexpr int FS    = 8782400;   // 1152 Smat
static constexpr int FW    = 8783552;   // 147200 fp32 weights
static constexpr int FATTB = 8930752;   // 262144 float-slots: att_bf (524288 ushort)
static constexpr int FWT   = 9192896;   // 61440 float-slots: Wt bf16 (122880 ushort)
// total = 9254336 floats = 37.0 MB

// ---- weight offsets inside FW ----
static constexpr int W_N1W=0, W_N1B=48, W_N2W=96, W_N2B=144;
static constexpr int W_KDW1=192, W_KDW2=4800, W_KC1A=5664, W_KC1B=10272;
static constexpr int W_KPROJ=11136, W_C2AW=15744, W_C2AB=16176;
static constexpr int W_C2BW=16200, W_C2BB=16584, W_C211W=16616, W_C211B=18152;
static constexpr int W_KW=18184, W_KB=128776, W_ATTG=131848, W_GA1=131880;
static constexpr int W_TEMP=131976, W_QKVW=131984, W_QKVDW=138896, W_MPROJ=140192;
static constexpr int W_CA1W=142496, W_CA1B=144800, W_CA2W=144848, W_CA2B=147152;

__device__ __forceinline__ float b2f(ushortT u) {
    union { uint32_t i; float f; } v; v.i = ((uint32_t)u) << 16; return v.f;
}
__device__ __forceinline__ ushortT f2b(float f) {
    union { float f; uint32_t i; } v; v.f = f;
    uint32_t i = v.i;
    uint32_t lsb = (i >> 16) & 1u;
    i += 0x7fffu + lsb;
    return (ushortT)(i >> 16);
}
__device__ __forceinline__ int dtype_bf16(const uint32_t* n1w_raw) {
    return n1w_raw[0] == 0x3F803F80u;   // bf16 ones pair vs fp32 1.0f
}

// ---------------- prep: weight convert (y<27) + Wt build (y==27) + gap (y==28) ----------------
struct ConvPack {
    const void* src[27];
    int dstoff[27];
    int n[27];
};

__global__ void k_prep(ConvPack p, float* __restrict__ dst, ushortT* __restrict__ Wt,
                       const void* __restrict__ x, float* __restrict__ gap,
                       const void* __restrict__ kw_raw, const void* __restrict__ kb_raw,
                       const uint32_t* __restrict__ n1w_raw) {
    int fl = dtype_bf16(n1w_raw);
    int y = blockIdx.y;
    if (y < 27) {
        int n = p.n[y];
        for (int i = blockIdx.x * 256 + threadIdx.x; i < n; i += 64 * 256) {
            float v;
            if (fl) v = b2f(((const ushortT*)p.src[y])[i]);
            else    v = ((const float*)p.src[y])[i];
            dst[p.dstoff[y] + i] = v;
        }
    } else if (y == 27) {
        // Wt[gr][r=j*4+i][n]: 24*160*32, read RAW kw/kb (no dep on convert)
        for (int u = blockIdx.x * 256 + threadIdx.x; u < 24 * 160 * 32; u += 64 * 256) {
            int n = u & 31;
            int rest = u >> 5;
            int r = rest % 160;
            int gr = rest / 160;
            ushortT out;
            if (r < 144) {
                int j = r >> 2, i = r & 3;
                int idx = n * 3456 + gr * 144 + i * 36 + j;
                out = fl ? ((const ushortT*)kw_raw)[idx] : f2b(((const float*)kw_raw)[idx]);
            } else if (r < 148) {
                int idx = n * HID + gr * 4 + (r - 144);
                out = fl ? ((const ushortT*)kb_raw)[idx] : f2b(((const float*)kb_raw)[idx]);
            } else out = 0;
            Wt[u] = out;
        }
    } else {
        // gap over H,W per (b,c): 192 reductions spread over 64 x-blocks
        __shared__ float red[4];
        for (int bc = blockIdx.x; bc < Bn * Cc; bc += 64) {
            float s = 0.f;
            if (fl) {
                const ushortT* xb = (const ushortT*)x + bc * HW;
                for (int i = threadIdx.x; i < HW; i += 256) s += b2f(xb[i]);
            } else {
                const float* xb = (const float*)x + bc * HW;
                for (int i = threadIdx.x; i < HW; i += 256) s += xb[i];
            }
            #pragma unroll
            for (int o = 32; o > 0; o >>= 1) s += __shfl_down(s, o);
            int lane = threadIdx.x & 63, wv = threadIdx.x >> 6;
            if (lane == 0) red[wv] = s;
            __syncthreads();
            if (threadIdx.x == 0)
                gap[bc] = (red[0] + red[1] + red[2] + red[3]) * (1.f / HW);
            __syncthreads();
        }
    }
}

// ---------------- pw1: LN1 inline; kdw1 (96), kc1a (96), c211 (32 -> [p][n]); y==0 writes xn ----------------
__global__ void __launch_bounds__(256) k_pw1(const void* __restrict__ x, const uint32_t* __restrict__ n1w_raw,
                      const float* __restrict__ wts, float* __restrict__ xn,
                      float* __restrict__ t1, float* __restrict__ t2, float* __restrict__ attn_t) {
    int fl = dtype_bf16(n1w_raw);
    int p = blockIdx.x * 256 + threadIdx.x;
    int b = p >> 12, hw = p & 4095;
    float xr[Cc];
    if (fl) {
        const ushortT* xb = (const ushortT*)x + b * Cc * HW + hw;
        #pragma unroll
        for (int c = 0; c < Cc; c++) xr[c] = b2f(xb[c * HW]);
    } else {
        const float* xb = (const float*)x + b * Cc * HW + hw;
        #pragma unroll
        for (int c = 0; c < Cc; c++) xr[c] = xb[c * HW];
    }
    float s = 0.f, ss = 0.f;
    #pragma unroll
    for (int c = 0; c < Cc; c++) { s += xr[c]; ss += xr[c] * xr[c]; }
    float mu = s * (1.f / Cc);
    float var = ss * (1.f / Cc) - mu * mu;
    float r = rsqrtf(var + 1e-6f);
    #pragma unroll
    for (int c = 0; c < Cc; c++)
        xr[c] = wts[W_N1W + c] * ((xr[c] - mu) * r) + wts[W_N1B + c];

    if (blockIdx.y == 0) {
        #pragma unroll
        for (int c = 0; c < Cc; c++) xn[(b * Cc + c) * HW + hw] = xr[c];
    }

    int co0 = blockIdx.y * 28;
    for (int kq = 0; kq < 7; kq++) {
        const float* wp[4]; float* dst[4]; float acc[4];
        #pragma unroll
        for (int i = 0; i < 4; i++) {
            int co = co0 + kq * 4 + i;
            if (co < 96) {
                wp[i] = wts + W_KDW1 + co * Cc; acc[i] = 0.f;
                dst[i] = t1 + (b * HID + co) * HW + hw;
            } else if (co < 192) {
                wp[i] = wts + W_KC1A + (co - 96) * Cc; acc[i] = 0.f;
                dst[i] = t2 + (b * HID + (co - 96)) * HW + hw;
            } else {
                wp[i] = wts + W_C211W + (co - 192) * Cc; acc[i] = wts[W_C211B + (co - 192)];
                dst[i] = attn_t + (size_t)p * 32 + (co - 192);
            }
        }
        #pragma unroll
        for (int c = 0; c < Cc; c++) {
            float xv = xr[c];
            #pragma unroll
            for (int i = 0; i < 4; i++) acc[i] += wp[i][c] * xv;
        }
        #pragma unroll
        for (int i = 0; i < 4; i++) *dst[i] = acc[i];
    }
}

// ---------------- depthwise 3x3: 4 px/thread, float4 IO. grid (16, 192) ----------------
__global__ void __launch_bounds__(256) k_dw(const float* __restrict__ t1, const float* __restrict__ t2,
                     const float* __restrict__ wts,
                     float* __restrict__ x1g, float* __restrict__ uf) {
    int y = blockIdx.y;   // 0..191
    int c = (y < 96) ? y : y - 96;
    const float* base = (y < 96) ? t1 : t2;
    const float* wk = wts + ((y < 96) ? W_KDW2 : W_KC1B) + c * 9;
    int pbase = blockIdx.x * 1024 + threadIdx.x * 4;
    int b = pbase >> 12, hw = pbase & 4095, h = hw >> 6, w0 = hw & 63;
    const float* plane = base + (b * HID + c) * HW;

    float a0 = 0.f, a1 = 0.f, a2 = 0.f, a3 = 0.f;
    #pragma unroll
    for (int ki = 0; ki < 3; ki++) {
        int hh = h + ki - 1;
        if ((unsigned)hh < 64u) {
            const float* row = plane + hh * 64 + w0;
            float4 m = *(const float4*)row;
            float lf = (w0 > 0) ? row[-1] : 0.f;
            float rt = (w0 < 60) ? row[4] : 0.f;
            float k0 = wk[ki * 3], k1 = wk[ki * 3 + 1], k2 = wk[ki * 3 + 2];
            a0 += k0 * lf  + k1 * m.x + k2 * m.y;
            a1 += k0 * m.x + k1 * m.y + k2 * m.z;
            a2 += k0 * m.y + k1 * m.z + k2 * m.w;
            a3 += k0 * m.z + k1 * m.w + k2 * rt;
        }
    }
    int idx = (b * HID + c) * HW + hw;
    if (y < 96) {
        float4 g;
        g.x = 0.5f * a0 * (1.f + erff(a0 * 0.70710678118654752f));
        g.y = 0.5f * a1 * (1.f + erff(a1 * 0.70710678118654752f));
        g.z = 0.5f * a2 * (1.f + erff(a2 * 0.70710678118654752f));
        g.w = 0.5f * a3 * (1.f + erff(a3 * 0.70710678118654752f));
        *(float4*)(x1g + idx) = g;
    } else {
        float4 o; o.x = a0; o.y = a1; o.z = a2; o.w = a3;
        *(float4*)(uf + idx) = o;
    }
}

// ---------------- attc: c2a(xn) -> SimpleGate -> c2b -> att (+c211) -> bf16 [p][n] ----------------
// grid 256 x 64 threads
__global__ void __launch_bounds__(64) k_attc(const float* __restrict__ xn, const float* __restrict__ attn_t,
                      const float* __restrict__ wts, ushortT* __restrict__ att_bf) {
    int p = blockIdx.x * 64 + threadIdx.x;
    int b = p >> 12, hw = p & 4095, h = hw >> 6, w = hw & 63;
    float ar[INTERC];
    for (int o = 0; o < INTERC; o++) {
        float acc = wts[W_C2AB + o];
        #pragma unroll
        for (int ic = 0; ic < 2; ic++) {
            const float* src = xn + (b * Cc + 2 * o + ic) * HW;
            const float* wk = wts + W_C2AW + (o * 2 + ic) * 9;
            #pragma unroll
            for (int ki = 0; ki < 3; ki++) {
                int hh = h + ki - 1;
                if ((unsigned)hh < 64u) {
                    #pragma unroll
                    for (int kj = 0; kj < 3; kj++) {
                        int ww = w + kj - 1;
                        if ((unsigned)ww < 64u) acc += wk[ki * 3 + kj] * src[hh * 64 + ww];
                    }
                }
            }
        }
        ar[o] = acc;
    }
    float sg[12];
    #pragma unroll
    for (int i = 0; i < 12; i++) sg[i] = ar[i] * ar[12 + i];
    const float* ct = attn_t + (size_t)p * 32;
    uint32_t packed[16];
    #pragma unroll
    for (int nq = 0; nq < 16; nq++) {
        float v2[2];
        #pragma unroll
        for (int u = 0; u < 2; u++) {
            int n = nq * 2 + u;
            float a = wts[W_C2BB + n];
            #pragma unroll
            for (int c = 0; c < 12; c++) a += wts[W_C2BW + n * 12 + c] * sg[c];
            v2[u] = wts[W_ATTG + n] * a + ct[n];
        }
        packed[nq] = (uint32_t)f2b(v2[0]) | ((uint32_t)f2b(v2[1]) << 16);
    }
    uint4* dst = (uint4*)(att_bf + (size_t)p * 32);
    #pragma unroll
    for (int q = 0; q < 4; q++) {
        uint4 v; v.x = packed[q*4]; v.y = packed[q*4+1]; v.z = packed[q*4+2]; v.w = packed[q*4+3];
        dst[q] = v;
    }
}

// ---------------- KBA core via MFMA (unchanged from r4, verified) ----------------
__global__ void __launch_bounds__(256) k_kba(const ushortT* __restrict__ att_bf, const float* __restrict__ uf,
                     const float* __restrict__ x1g, const ushortT* __restrict__ Wt,
                     const float* __restrict__ wts, float* __restrict__ hbuf) {
    int wave = threadIdx.x >> 6, lane = threadIdx.x & 63;
    int m = lane & 15, q = lane >> 4;
    int gr = blockIdx.y;   // 0..23

    short8 A[10];
    const ushortT* wtg = Wt + gr * 160 * 32;
    #pragma unroll
    for (int t = 0; t < 10; t++)
        A[t] = *(const short8*)(wtg + (16 * t + m) * 32 + q * 8);

    for (int tile = 0; tile < 4; tile++) {
        int p = blockIdx.x * 256 + wave * 64 + tile * 16 + m;
        int b = p >> 12, hw = p & 4095, h = hw >> 6, w = hw & 63;

        short8 Bf = *(const short8*)(att_bf + (size_t)p * 32 + q * 8);

        f32x4 D[10];
        #pragma unroll
        for (int t = 0; t < 10; t++) {
            f32x4 z = {0.f, 0.f, 0.f, 0.f};
            D[t] = __builtin_amdgcn_mfma_f32_16x16x32_bf16(A[t], Bf, z, 0, 0, 0);
        }

        float s0 = 0.f, s1 = 0.f, s2 = 0.f, s3 = 0.f;
        #pragma unroll
        for (int t = 0; t < 9; t++) {
            int j = 4 * t + q;
            int ci = j / 9;
            int kk = j - 9 * ci;
            int ki = kk / 3, kj = kk - 3 * ki;
            int hh = h + ki - 1, ww = w + kj - 1;
            float tap = 0.f;
            if ((unsigned)hh < 64u && (unsigned)ww < 64u)
                tap = uf[(b * HID + gr * 4 + ci) * HW + hh * 64 + ww];
            s0 += D[t][0] * tap;
            s1 += D[t][1] * tap;
            s2 += D[t][2] * tap;
            s3 += D[t][3] * tap;
        }
        s0 += D[9][0]; s1 += D[9][1]; s2 += D[9][2]; s3 += D[9][3];

        s0 += __shfl_xor(s0, 16); s0 += __shfl_xor(s0, 32);
        s1 += __shfl_xor(s1, 16); s1 += __shfl_xor(s1, 32);
        s2 += __shfl_xor(s2, 16); s2 += __shfl_xor(s2, 32);
        s3 += __shfl_xor(s3, 16); s3 += __shfl_xor(s3, 32);

        float sel = (q == 0) ? s0 : ((q == 1) ? s1 : ((q == 2) ? s2 : s3));
        int ch = gr * 4 + q;
        int idx = (b * HID + ch) * HW + hw;
        float ufc = uf[idx];
        float x2 = sel * wts[W_GA1 + ch] + ufc;
        hbuf[idx] = x1g[idx] * x2;
    }
}

// ---------------- kproj 1x1 (96 -> 48) ----------------
__global__ void __launch_bounds__(256) k_kproj(const float* __restrict__ hbuf, const float* __restrict__ wts,
                        float* __restrict__ kba) {
    int p = blockIdx.x * 256 + threadIdx.x;
    int b = p >> 12, hw = p & 4095;
    const float* hb = hbuf + b * HID * HW + hw;
    int co0 = blockIdx.y * 12;
    float acc[12];
    #pragma unroll
    for (int k = 0; k < 12; k++) acc[k] = 0.f;
    for (int c = 0; c < HID; c++) {
        float hv = hb[c * HW];
        #pragma unroll
        for (int k = 0; k < 12; k++)
            acc[k] += wts[W_KPROJ + (co0 + k) * HID + c] * hv;
    }
    #pragma unroll
    for (int k = 0; k < 12; k++)
        kba[(b * Cc + co0 + k) * HW + hw] = acc[k];
}

// ---------------- qkv pointwise (LN2 inline; 48 -> 144) ----------------
__global__ void __launch_bounds__(256) k_qkvpw(const void* __restrict__ x, const uint32_t* __restrict__ n1w_raw,
                        const float* __restrict__ wts, float* __restrict__ qkvr) {
    int fl = dtype_bf16(n1w_raw);
    int p = blockIdx.x * 256 + threadIdx.x;
    int b = p >> 12, hw = p & 4095;
    float xr[Cc];
    if (fl) {
        const ushortT* xb = (const ushortT*)x + b * Cc * HW + hw;
        #pragma unroll
        for (int c = 0; c < Cc; c++) xr[c] = b2f(xb[c * HW]);
    } else {
        const float* xb = (const float*)x + b * Cc * HW + hw;
        #pragma unroll
        for (int c = 0; c < Cc; c++) xr[c] = xb[c * HW];
    }
    float s = 0.f, ss = 0.f;
    #pragma unroll
    for (int c = 0; c < Cc; c++) { s += xr[c]; ss += xr[c] * xr[c]; }
    float mu = s * (1.f / Cc);
    float var = ss * (1.f / Cc) - mu * mu;
    float r = rsqrtf(var + 1e-6f);
    #pragma unroll
    for (int c = 0; c < Cc; c++)
        xr[c] = wts[W_N2W + c] * ((xr[c] - mu) * r) + wts[W_N2B + c];

    int co0 = blockIdx.y * 24;
    for (int kq = 0; kq < 6; kq++) {
        float acc[4] = {0.f, 0.f, 0.f, 0.f};
        #pragma unroll
        for (int c = 0; c < Cc; c++) {
            float xv = xr[c];
            #pragma unroll
            for (int i = 0; i < 4; i++)
                acc[i] += wts[W_QKVW + (co0 + kq * 4 + i) * Cc + c] * xv;
        }
        #pragma unroll
        for (int i = 0; i < 4; i++)
            qkvr[(b * 144 + co0 + kq * 4 + i) * HW + hw] = acc[i];
    }
}

// ---------------- qkv depthwise 3x3: 4 px/thread float4. grid (16, 144) ----------------
__global__ void __launch_bounds__(256) k_qkvdw(const float* __restrict__ qkvr, const float* __restrict__ wts,
                        float* __restrict__ qkv) {
    int ch = blockIdx.y;   // 0..143
    const float* wk = wts + W_QKVDW + ch * 9;
    int pbase = blockIdx.x * 1024 + threadIdx.x * 4;
    int b = pbase >> 12, hw = pbase & 4095, h = hw >> 6, w0 = hw & 63;
    const float* plane = qkvr + (b * 144 + ch) * HW;

    float a0 = 0.f, a1 = 0.f, a2 = 0.f, a3 = 0.f;
    #pragma unroll
    for (int ki = 0; ki < 3; ki++) {
        int hh = h + ki - 1;
        if ((unsigned)hh < 64u) {
            const float* row = plane + hh * 64 + w0;
            float4 m = *(const float4*)row;
            float lf = (w0 > 0) ? row[-1] : 0.f;
            float rt = (w0 < 60) ? row[4] : 0.f;
            float k0 = wk[ki * 3], k1 = wk[ki * 3 + 1], k2 = wk[ki * 3 + 2];
            a0 += k0 * lf  + k1 * m.x + k2 * m.y;
            a1 += k0 * m.x + k1 * m.y + k2 * m.z;
            a2 += k0 * m.y + k1 * m.z + k2 * m.w;
            a3 += k0 * m.z + k1 * m.w + k2 * rt;
        }
    }
    float4 o; o.x = a0; o.y = a1; o.z = a2; o.w = a3;
    *(float4*)(qkv + (b * 144 + ch) * HW + hw) = o;
}

// ---------------- S partials + q/k norm partials: grid (32 bh, 8 chunks) x 256 ----------------
__global__ void k_smat1(const float* __restrict__ qkv, float* __restrict__ Sp) {
    int bh = blockIdx.x, chunk = blockIdx.y;
    int b = bh / HEADS, hd = bh % HEADS;
    const float* qb = qkv + (b * 144 + hd * CPH) * HW;
    const float* kb = qkv + (b * 144 + 48 + hd * CPH) * HW;
    float acc[48];
    #pragma unroll
    for (int t = 0; t < 48; t++) acc[t] = 0.f;
    int base = chunk * 512;
    for (int i = threadIdx.x; i < 512; i += 256) {
        int px = base + i;
        float qv[CPH], kv[CPH];
        #pragma unroll
        for (int c = 0; c < CPH; c++) { qv[c] = qb[c * HW + px]; kv[c] = kb[c * HW + px]; }
        #pragma unroll
        for (int c = 0; c < CPH; c++) {
            #pragma unroll
            for (int d = 0; d < CPH; d++) acc[c * CPH + d] += qv[c] * kv[d];
            acc[36 + c] += qv[c] * qv[c];
            acc[42 + c] += kv[c] * kv[c];
        }
    }
    __shared__ float red[48 * 4];
    int lane = threadIdx.x & 63, wv = threadIdx.x >> 6;
    #pragma unroll
    for (int t = 0; t < 48; t++) {
        float v = acc[t];
        #pragma unroll
        for (int o = 32; o > 0; o >>= 1) v += __shfl_down(v, o);
        if (lane == 0) red[t * 4 + wv] = v;
    }
    __syncthreads();
    if (threadIdx.x < 48)
        Sp[(bh * 8 + chunk) * 48 + threadIdx.x] =
            red[threadIdx.x * 4] + red[threadIdx.x * 4 + 1] +
            red[threadIdx.x * 4 + 2] + red[threadIdx.x * 4 + 3];
}

// ---------------- finalize softmax S (+ channel attention ca1/ca2) ----------------
__global__ void k_smat2(const float* __restrict__ Sp, const float* __restrict__ gap,
                        const float* __restrict__ wts, float* __restrict__ S,
                        float* __restrict__ ca1, float* __restrict__ ca2) {
    int bh = blockIdx.x;
    int b = bh / HEADS, hd = bh % HEADS;
    int t = threadIdx.x;   // 64 threads
    __shared__ float sm[48];
    if (t < 48) {
        float v = 0.f;
        #pragma unroll
        for (int ch = 0; ch < 8; ch++) v += Sp[(bh * 8 + ch) * 48 + t];
        sm[t] = v;
    }
    __syncthreads();
    if (t < CPH) {
        float rqv = 1.f / fmaxf(sqrtf(sm[36 + t]), 1e-12f);
        float tmp = wts[W_TEMP + hd];
        float row[CPH];
        #pragma unroll
        for (int d = 0; d < CPH; d++) {
            float rkv = 1.f / fmaxf(sqrtf(sm[42 + d]), 1e-12f);
            row[d] = sm[t * CPH + d] * rqv * rkv * tmp;
        }
        float mx = row[0];
        #pragma unroll
        for (int d = 1; d < CPH; d++) mx = fmaxf(mx, row[d]);
        float sum = 0.f;
        #pragma unroll
        for (int d = 0; d < CPH; d++) { row[d] = expf(row[d] - mx); sum += row[d]; }
        float inv = 1.f / sum;
        #pragma unroll
        for (int d = 0; d < CPH; d++) S[bh * 36 + t * CPH + d] = row[d] * inv;
    }
    if (t >= 52 && t < 64) {
        int idx = t - 52;
        int which = idx / 6, cc = idx % 6;
        int co = hd * CPH + cc;
        const float* g = gap + b * Cc;
        float sacc = wts[(which ? W_CA2B : W_CA1B) + co];
        #pragma unroll
        for (int c = 0; c < Cc; c++)
            sacc += wts[(which ? W_CA2W : W_CA1W) + co * Cc + c] * g[c];
        (which ? ca2 : ca1)[b * Cc + co] = sacc;
    }
}

// ---------------- attn out: mdta = S @ v. grid (64, 8) ----------------
__global__ void __launch_bounds__(256) k_attout(const float* __restrict__ qkv, const float* __restrict__ S,
                         float* __restrict__ mdta) {
    int p = blockIdx.x * 256 + threadIdx.x;
    int b = p >> 12, hw = p & 4095;
    int hd = blockIdx.y;
    const float* vb = qkv + (b * 144 + 96 + hd * CPH) * HW + hw;
    float vv[CPH];
    #pragma unroll
    for (int d = 0; d < CPH; d++) vv[d] = vb[d * HW];
    const float* Sb = S + (b * HEADS + hd) * 36;
    #pragma unroll
    for (int c = 0; c < CPH; c++) {
        float acc = 0.f;
        #pragma unroll
        for (int d = 0; d < CPH; d++) acc += Sb[c * CPH + d] * vv[d];
        mdta[(b * Cc + hd * CPH + c) * HW + hw] = acc;
    }
}

// ---------------- final: out = x + kba*ca1 + mproj(mdta)*ca2. grid (64, 4) ----------------
__global__ void __launch_bounds__(256) k_final(const void* __restrict__ x, const uint32_t* __restrict__ n1w_raw,
                        const float* __restrict__ kba, const float* __restrict__ mdta,
                        const float* __restrict__ wts, const float* __restrict__ ca1,
                        const float* __restrict__ ca2, void* __restrict__ out) {
    int fl = dtype_bf16(n1w_raw);
    int p = blockIdx.x * 256 + threadIdx.x;
    int b = p >> 12, hw = p & 4095;
    const float* mb = mdta + b * Cc * HW + hw;
    int co0 = blockIdx.y * 12;
    float acc[12];
    #pragma unroll
    for (int k = 0; k < 12; k++) acc[k] = 0.f;
    for (int c = 0; c < Cc; c++) {
        float mv = mb[c * HW];
        #pragma unroll
        for (int k = 0; k < 12; k++)
            acc[k] += wts[W_MPROJ + (co0 + k) * Cc + c] * mv;
    }
    #pragma unroll
    for (int k = 0; k < 12; k++) {
        int co = co0 + k;
        int idx = (b * Cc + co) * HW + hw;
        float xv = fl ? b2f(((const ushortT*)x)[idx]) : ((const float*)x)[idx];
        float res = xv + kba[idx] * ca1[b * Cc + co] + acc[k] * ca2[b * Cc + co];
        if (fl) ((ushortT*)out)[idx] = f2b(res);
        else    ((float*)out)[idx] = res;
    }
}

// ---------------- host launch ----------------
extern "C" void kernel_launch(void* const* d_in, const int* in_sizes, int n_in,
                              void* d_out, int out_size, void* d_ws, size_t ws_size,
                              hipStream_t stream) {
    float* ws_f = (float*)d_ws;

    float* xn    = ws_f + FXN;    // later mdta
    float* bufA  = ws_f + FA;     // t1 -> hbuf -> qkvr -> Sp
    float* bufB  = ws_f + FB;     // t2
    float* bufC  = ws_f + FC;     // x1g -> qkv
    float* bufD  = ws_f + FD;     // uf
    float* attn_t= ws_f + FATT;
    float* kba   = ws_f + FKBA;
    float* gap   = ws_f + FGAP;
    float* ca1   = ws_f + FCA1;
    float* ca2   = ws_f + FCA2;
    float* Smat  = ws_f + FS;
    float* wts   = ws_f + FW;
    ushortT* att_bf = (ushortT*)(ws_f + FATTB);
    ushortT* Wt     = (ushortT*)(ws_f + FWT);

    float* qkvr = bufA;
    float* qkv  = bufC;
    float* Sp   = bufA;
    float* mdta = xn;
    const uint32_t* n1w_raw = (const uint32_t*)d_in[1];

    static const int wsizes[27] = {48,48,48,48,4608,864,4608,864,4608,432,24,384,32,
                                   1536,32,110592,3072,32,96,8,6912,1296,2304,2304,48,2304,48};
    static const int woffs[27] = {W_N1W,W_N1B,W_N2W,W_N2B,W_KDW1,W_KDW2,W_KC1A,W_KC1B,
                                  W_KPROJ,W_C2AW,W_C2AB,W_C2BW,W_C2BB,W_C211W,W_C211B,
                                  W_KW,W_KB,W_ATTG,W_GA1,W_TEMP,W_QKVW,W_QKVDW,W_MPROJ,
                                  W_CA1W,W_CA1B,W_CA2W,W_CA2B};
    ConvPack cp;
    for (int i = 0; i < 27; i++) {
        cp.src[i] = d_in[i + 1];
        cp.dstoff[i] = woffs[i];
        cp.n[i] = wsizes[i];
    }

    k_prep<<<dim3(64, 29), 256, 0, stream>>>(cp, wts, Wt, d_in[0], gap,
                                             d_in[16], d_in[17], n1w_raw);
    k_pw1<<<dim3(64, 8), 256, 0, stream>>>(d_in[0], n1w_raw, wts, xn, bufA, bufB, attn_t);
    k_dw<<<dim3(16, 192), 256, 0, stream>>>(bufA, bufB, wts, bufC, bufD);
    k_attc<<<dim3(256), 64, 0, stream>>>(xn, attn_t, wts, att_bf);
    k_kba<<<dim3(64, 24), 256, 0, stream>>>(att_bf, bufD, bufC, Wt, wts, bufA);
    k_kproj<<<dim3(64, 4), 256, 0, stream>>>(bufA, wts, kba);
    k_qkvpw<<<dim3(64, 6), 256, 0, stream>>>(d_in[0], n1w_raw, wts, qkvr);
    k_qkvdw<<<dim3(16, 144), 256, 0, stream>>>(qkvr, wts, qkv);
    k_smat1<<<dim3(32, 8), 256, 0, stream>>>(qkv, Sp);
    k_smat2<<<dim3(32), 64, 0, stream>>>(Sp, gap, wts, Smat, ca1, ca2);
    k_attout<<<dim3(64, 8), 256, 0, stream>>>(qkv, Smat, mdta);
    k_final<<<dim3(64, 4), 256, 0, stream>>>(d_in[0], n1w_raw, kba, mdta, wts, ca1, ca2, d_out);
}

// Round 6
// 278.182 us; speedup vs baseline: 1.2387x; 1.2387x over previous
//
#include <hip/hip_runtime.h>
#include <hip/hip_bf16.h>
#include <cstdint>

typedef unsigned short ushortT;
typedef __attribute__((ext_vector_type(8))) short short8;
typedef __attribute__((ext_vector_type(4))) float f32x4;

// ---------------- problem constants ----------------
static constexpr int Bn = 4, Cc = 48, Hh = 64, Wd = 64, HW = 4096;
static constexpr int HID = 96, NSET = 32, INTERC = 24, HEADS = 8, CPH = 6;

// ---------------- ws layout (float offsets) ----------------
static constexpr int FXN   = 0;         // 786432  xn ; later mdta
static constexpr int FA    = 786432;    // 1572864 t1 -> hbuf -> qkvr(lo) -> Sp
static constexpr int FB    = 2359296;   // 1572864 t2 -> qkvr(hi)
static constexpr int FC    = 3932160;   // 1572864 x1g -> qkv(lo)
static constexpr int FD    = 5505024;   // 1572864 uf -> qkv(hi)
static constexpr int FARAW = 7077888;   // 393216  c2a out
static constexpr int FATT  = 7471104;   // 524288  attn_t fp32 [p][n]
static constexpr int FKBA  = 7995392;   // 786432
static constexpr int FGAP  = 8781824;   // 192
static constexpr int FCA1  = 8782016;   // 192
static constexpr int FCA2  = 8782208;   // 192
static constexpr int FS    = 8782400;   // 1152 Smat
static constexpr int FW    = 8783552;   // 147200 fp32 weights
static constexpr int FATTB = 8930752;   // 262144 float-slots: att_bf (524288 ushort)
static constexpr int FWT   = 9192896;   // 61440 float-slots: Wt bf16 (122880 ushort)
// total = 9254336 floats = 37.0 MB

// ---- weight offsets inside FW ----
static constexpr int W_N1W=0, W_N1B=48, W_N2W=96, W_N2B=144;
static constexpr int W_KDW1=192, W_KDW2=4800, W_KC1A=5664, W_KC1B=10272;
static constexpr int W_KPROJ=11136, W_C2AW=15744, W_C2AB=16176;
static constexpr int W_C2BW=16200, W_C2BB=16584, W_C211W=16616, W_C211B=18152;
static constexpr int W_KW=18184, W_KB=128776, W_ATTG=131848, W_GA1=131880;
static constexpr int W_TEMP=131976, W_QKVW=131984, W_QKVDW=138896, W_MPROJ=140192;
static constexpr int W_CA1W=142496, W_CA1B=144800, W_CA2W=144848, W_CA2B=147152;

__device__ __forceinline__ float b2f(ushortT u) {
    union { uint32_t i; float f; } v; v.i = ((uint32_t)u) << 16; return v.f;
}
__device__ __forceinline__ ushortT f2b(float f) {
    union { float f; uint32_t i; } v; v.f = f;
    uint32_t i = v.i;
    uint32_t lsb = (i >> 16) & 1u;
    i += 0x7fffu + lsb;
    return (ushortT)(i >> 16);
}
__device__ __forceinline__ int dtype_bf16(const uint32_t* n1w_raw) {
    return n1w_raw[0] == 0x3F803F80u;   // bf16 ones pair vs fp32 1.0f
}

// ---------------- prep: weight convert (y<27) + Wt build (y==27) + gap (y==28) ----------------
struct ConvPack {
    const void* src[27];
    int dstoff[27];
    int n[27];
};

__global__ void k_prep(ConvPack p, float* __restrict__ dst, ushortT* __restrict__ Wt,
                       const void* __restrict__ x, float* __restrict__ gap,
                       const void* __restrict__ kw_raw, const void* __restrict__ kb_raw,
                       const uint32_t* __restrict__ n1w_raw) {
    int fl = dtype_bf16(n1w_raw);
    int y = blockIdx.y;
    if (y < 27) {
        int n = p.n[y];
        for (int i = blockIdx.x * 256 + threadIdx.x; i < n; i += 64 * 256) {
            float v;
            if (fl) v = b2f(((const ushortT*)p.src[y])[i]);
            else    v = ((const float*)p.src[y])[i];
            dst[p.dstoff[y] + i] = v;
        }
    } else if (y == 27) {
        // Wt[gr][r=j*4+i][n]: 24*160*32, read RAW kw/kb (no dep on convert)
        for (int u = blockIdx.x * 256 + threadIdx.x; u < 24 * 160 * 32; u += 64 * 256) {
            int n = u & 31;
            int rest = u >> 5;
            int r = rest % 160;
            int gr = rest / 160;
            ushortT out;
            if (r < 144) {
                int j = r >> 2, i = r & 3;
                int idx = n * 3456 + gr * 144 + i * 36 + j;
                out = fl ? ((const ushortT*)kw_raw)[idx] : f2b(((const float*)kw_raw)[idx]);
            } else if (r < 148) {
                int idx = n * HID + gr * 4 + (r - 144);
                out = fl ? ((const ushortT*)kb_raw)[idx] : f2b(((const float*)kb_raw)[idx]);
            } else out = 0;
            Wt[u] = out;
        }
    } else {
        // gap over H,W per (b,c): 192 reductions spread over 64 x-blocks
        __shared__ float red[4];
        for (int bc = blockIdx.x; bc < Bn * Cc; bc += 64) {
            float s = 0.f;
            if (fl) {
                const ushortT* xb = (const ushortT*)x + bc * HW;
                for (int i = threadIdx.x; i < HW; i += 256) s += b2f(xb[i]);
            } else {
                const float* xb = (const float*)x + bc * HW;
                for (int i = threadIdx.x; i < HW; i += 256) s += xb[i];
            }
            #pragma unroll
            for (int o = 32; o > 0; o >>= 1) s += __shfl_down(s, o);
            int lane = threadIdx.x & 63, wv = threadIdx.x >> 6;
            if (lane == 0) red[wv] = s;
            __syncthreads();
            if (threadIdx.x == 0)
                gap[bc] = (red[0] + red[1] + red[2] + red[3]) * (1.f / HW);
            __syncthreads();
        }
    }
}

// ---------------- pw1: LN1 inline; kdw1 (96), kc1a (96), c211 (32 -> [p][n]); y==0 writes xn ----------------
__global__ void __launch_bounds__(256) k_pw1(const void* __restrict__ x, const uint32_t* __restrict__ n1w_raw,
                      const float* __restrict__ wts, float* __restrict__ xn,
                      float* __restrict__ t1, float* __restrict__ t2, float* __restrict__ attn_t) {
    int fl = dtype_bf16(n1w_raw);
    int p = blockIdx.x * 256 + threadIdx.x;
    int b = p >> 12, hw = p & 4095;
    float xr[Cc];
    if (fl) {
        const ushortT* xb = (const ushortT*)x + b * Cc * HW + hw;
        #pragma unroll
        for (int c = 0; c < Cc; c++) xr[c] = b2f(xb[c * HW]);
    } else {
        const float* xb = (const float*)x + b * Cc * HW + hw;
        #pragma unroll
        for (int c = 0; c < Cc; c++) xr[c] = xb[c * HW];
    }
    float s = 0.f, ss = 0.f;
    #pragma unroll
    for (int c = 0; c < Cc; c++) { s += xr[c]; ss += xr[c] * xr[c]; }
    float mu = s * (1.f / Cc);
    float var = ss * (1.f / Cc) - mu * mu;
    float r = rsqrtf(var + 1e-6f);
    #pragma unroll
    for (int c = 0; c < Cc; c++)
        xr[c] = wts[W_N1W + c] * ((xr[c] - mu) * r) + wts[W_N1B + c];

    if (blockIdx.y == 0) {
        #pragma unroll
        for (int c = 0; c < Cc; c++) xn[(b * Cc + c) * HW + hw] = xr[c];
    }

    int co0 = blockIdx.y * 28;
    for (int kq = 0; kq < 7; kq++) {
        const float* wp[4]; float* dst[4]; float acc[4];
        #pragma unroll
        for (int i = 0; i < 4; i++) {
            int co = co0 + kq * 4 + i;
            if (co < 96) {
                wp[i] = wts + W_KDW1 + co * Cc; acc[i] = 0.f;
                dst[i] = t1 + (b * HID + co) * HW + hw;
            } else if (co < 192) {
                wp[i] = wts + W_KC1A + (co - 96) * Cc; acc[i] = 0.f;
                dst[i] = t2 + (b * HID + (co - 96)) * HW + hw;
            } else {
                wp[i] = wts + W_C211W + (co - 192) * Cc; acc[i] = wts[W_C211B + (co - 192)];
                dst[i] = attn_t + (size_t)p * 32 + (co - 192);
            }
        }
        #pragma unroll
        for (int c = 0; c < Cc; c++) {
            float xv = xr[c];
            #pragma unroll
            for (int i = 0; i < 4; i++) acc[i] += wp[i][c] * xv;
        }
        #pragma unroll
        for (int i = 0; i < 4; i++) *dst[i] = acc[i];
    }
}

// ---------------- depthwise/grouped 3x3: 4 px/thread, float4 IO. grid (16, 216) ----------------
// y<96: kdw2(t1)->gelu->x1g ; y<192: kc1b(t2)->uf ; y>=192: c2a(xn)->araw
__global__ void __launch_bounds__(256) k_dw(const float* __restrict__ t1, const float* __restrict__ t2,
                     const float* __restrict__ xn, const float* __restrict__ wts,
                     float* __restrict__ x1g, float* __restrict__ uf, float* __restrict__ araw) {
    int y = blockIdx.y;   // 0..215
    int pbase = blockIdx.x * 1024 + threadIdx.x * 4;
    int b = pbase >> 12, hw = pbase & 4095, h = hw >> 6, w0 = hw & 63;

    if (y < 192) {
        int c = (y < 96) ? y : y - 96;
        const float* base = (y < 96) ? t1 : t2;
        const float* wk = wts + ((y < 96) ? W_KDW2 : W_KC1B) + c * 9;
        const float* plane = base + (b * HID + c) * HW;

        float a0 = 0.f, a1 = 0.f, a2 = 0.f, a3 = 0.f;
        #pragma unroll
        for (int ki = 0; ki < 3; ki++) {
            int hh = h + ki - 1;
            if ((unsigned)hh < 64u) {
                const float* row = plane + hh * 64 + w0;
                float4 m = *(const float4*)row;
                float lf = (w0 > 0) ? row[-1] : 0.f;
                float rt = (w0 < 60) ? row[4] : 0.f;
                float k0 = wk[ki * 3], k1 = wk[ki * 3 + 1], k2 = wk[ki * 3 + 2];
                a0 += k0 * lf  + k1 * m.x + k2 * m.y;
                a1 += k0 * m.x + k1 * m.y + k2 * m.z;
                a2 += k0 * m.y + k1 * m.z + k2 * m.w;
                a3 += k0 * m.z + k1 * m.w + k2 * rt;
            }
        }
        int idx = (b * HID + c) * HW + hw;
        if (y < 96) {
            float4 g;
            g.x = 0.5f * a0 * (1.f + erff(a0 * 0.70710678118654752f));
            g.y = 0.5f * a1 * (1.f + erff(a1 * 0.70710678118654752f));
            g.z = 0.5f * a2 * (1.f + erff(a2 * 0.70710678118654752f));
            g.w = 0.5f * a3 * (1.f + erff(a3 * 0.70710678118654752f));
            *(float4*)(x1g + idx) = g;
        } else {
            float4 o; o.x = a0; o.y = a1; o.z = a2; o.w = a3;
            *(float4*)(uf + idx) = o;
        }
    } else {
        int o = y - 192;   // 0..23
        float bias = wts[W_C2AB + o];
        float a0 = bias, a1 = bias, a2 = bias, a3 = bias;
        #pragma unroll
        for (int ic = 0; ic < 2; ic++) {
            const float* plane = xn + (b * Cc + 2 * o + ic) * HW;
            const float* wk = wts + W_C2AW + (o * 2 + ic) * 9;
            #pragma unroll
            for (int ki = 0; ki < 3; ki++) {
                int hh = h + ki - 1;
                if ((unsigned)hh < 64u) {
                    const float* row = plane + hh * 64 + w0;
                    float4 m = *(const float4*)row;
                    float lf = (w0 > 0) ? row[-1] : 0.f;
                    float rt = (w0 < 60) ? row[4] : 0.f;
                    float k0 = wk[ki * 3], k1 = wk[ki * 3 + 1], k2 = wk[ki * 3 + 2];
                    a0 += k0 * lf  + k1 * m.x + k2 * m.y;
                    a1 += k0 * m.x + k1 * m.y + k2 * m.z;
                    a2 += k0 * m.y + k1 * m.z + k2 * m.w;
                    a3 += k0 * m.z + k1 * m.w + k2 * rt;
                }
            }
        }
        float4 out; out.x = a0; out.y = a1; out.z = a2; out.w = a3;
        *(float4*)(araw + (b * INTERC + o) * HW + hw) = out;
    }
}

// ---------------- att = attgamma * c2b(SimpleGate(araw)) + c211; emit bf16 [p][n]. grid (64) x 256 ----------------
__global__ void __launch_bounds__(256) k_att(const float* __restrict__ araw, const float* __restrict__ attn_t,
                     const float* __restrict__ wts, ushortT* __restrict__ att_bf) {
    int p = blockIdx.x * 256 + threadIdx.x;
    int b = p >> 12, hw = p & 4095;
    const float* ab = araw + b * INTERC * HW + hw;
    float sg[12];
    #pragma unroll
    for (int i = 0; i < 12; i++) sg[i] = ab[i * HW] * ab[(12 + i) * HW];
    const float* ct = attn_t + (size_t)p * 32;
    uint32_t packed[16];
    #pragma unroll
    for (int nq = 0; nq < 16; nq++) {
        float v2[2];
        #pragma unroll
        for (int u = 0; u < 2; u++) {
            int n = nq * 2 + u;
            float a = wts[W_C2BB + n];
            #pragma unroll
            for (int c = 0; c < 12; c++) a += wts[W_C2BW + n * 12 + c] * sg[c];
            v2[u] = wts[W_ATTG + n] * a + ct[n];
        }
        packed[nq] = (uint32_t)f2b(v2[0]) | ((uint32_t)f2b(v2[1]) << 16);
    }
    uint4* dst = (uint4*)(att_bf + (size_t)p * 32);
    #pragma unroll
    for (int q = 0; q < 4; q++) {
        uint4 v; v.x = packed[q*4]; v.y = packed[q*4+1]; v.z = packed[q*4+2]; v.w = packed[q*4+3];
        dst[q] = v;
    }
}

// ---------------- KBA core via MFMA (verified r4) ----------------
__global__ void __launch_bounds__(256) k_kba(const ushortT* __restrict__ att_bf, const float* __restrict__ uf,
                     const float* __restrict__ x1g, const ushortT* __restrict__ Wt,
                     const float* __restrict__ wts, float* __restrict__ hbuf) {
    int wave = threadIdx.x >> 6, lane = threadIdx.x & 63;
    int m = lane & 15, q = lane >> 4;
    int gr = blockIdx.y;   // 0..23

    short8 A[10];
    const ushortT* wtg = Wt + gr * 160 * 32;
    #pragma unroll
    for (int t = 0; t < 10; t++)
        A[t] = *(const short8*)(wtg + (16 * t + m) * 32 + q * 8);

    for (int tile = 0; tile < 4; tile++) {
        int p = blockIdx.x * 256 + wave * 64 + tile * 16 + m;
        int b = p >> 12, hw = p & 4095, h = hw >> 6, w = hw & 63;

        short8 Bf = *(const short8*)(att_bf + (size_t)p * 32 + q * 8);

        f32x4 D[10];
        #pragma unroll
        for (int t = 0; t < 10; t++) {
            f32x4 z = {0.f, 0.f, 0.f, 0.f};
            D[t] = __builtin_amdgcn_mfma_f32_16x16x32_bf16(A[t], Bf, z, 0, 0, 0);
        }

        float s0 = 0.f, s1 = 0.f, s2 = 0.f, s3 = 0.f;
        #pragma unroll
        for (int t = 0; t < 9; t++) {
            int j = 4 * t + q;
            int ci = j / 9;
            int kk = j - 9 * ci;
            int ki = kk / 3, kj = kk - 3 * ki;
            int hh = h + ki - 1, ww = w + kj - 1;
            float tap = 0.f;
            if ((unsigned)hh < 64u && (unsigned)ww < 64u)
                tap = uf[(b * HID + gr * 4 + ci) * HW + hh * 64 + ww];
            s0 += D[t][0] * tap;
            s1 += D[t][1] * tap;
            s2 += D[t][2] * tap;
            s3 += D[t][3] * tap;
        }
        s0 += D[9][0]; s1 += D[9][1]; s2 += D[9][2]; s3 += D[9][3];

        s0 += __shfl_xor(s0, 16); s0 += __shfl_xor(s0, 32);
        s1 += __shfl_xor(s1, 16); s1 += __shfl_xor(s1, 32);
        s2 += __shfl_xor(s2, 16); s2 += __shfl_xor(s2, 32);
        s3 += __shfl_xor(s3, 16); s3 += __shfl_xor(s3, 32);

        float sel = (q == 0) ? s0 : ((q == 1) ? s1 : ((q == 2) ? s2 : s3));
        int ch = gr * 4 + q;
        int idx = (b * HID + ch) * HW + hw;
        float ufc = uf[idx];
        float x2 = sel * wts[W_GA1 + ch] + ufc;
        hbuf[idx] = x1g[idx] * x2;
    }
}

// ---------------- kproj 1x1 (96 -> 48): grid (64, 8), 6 outs/thread ----------------
__global__ void __launch_bounds__(256) k_kproj(const float* __restrict__ hbuf, const float* __restrict__ wts,
                        float* __restrict__ kba) {
    int p = blockIdx.x * 256 + threadIdx.x;
    int b = p >> 12, hw = p & 4095;
    const float* hb = hbuf + b * HID * HW + hw;
    int co0 = blockIdx.y * 6;
    float acc[6];
    #pragma unroll
    for (int k = 0; k < 6; k++) acc[k] = 0.f;
    for (int c = 0; c < HID; c++) {
        float hv = hb[c * HW];
        #pragma unroll
        for (int k = 0; k < 6; k++)
            acc[k] += wts[W_KPROJ + (co0 + k) * HID + c] * hv;
    }
    #pragma unroll
    for (int k = 0; k < 6; k++)
        kba[(b * Cc + co0 + k) * HW + hw] = acc[k];
}

// ---------------- qkv pointwise (LN2 inline; 48 -> 144) ----------------
__global__ void __launch_bounds__(256) k_qkvpw(const void* __restrict__ x, const uint32_t* __restrict__ n1w_raw,
                        const float* __restrict__ wts, float* __restrict__ qkvr) {
    int fl = dtype_bf16(n1w_raw);
    int p = blockIdx.x * 256 + threadIdx.x;
    int b = p >> 12, hw = p & 4095;
    float xr[Cc];
    if (fl) {
        const ushortT* xb = (const ushortT*)x + b * Cc * HW + hw;
        #pragma unroll
        for (int c = 0; c < Cc; c++) xr[c] = b2f(xb[c * HW]);
    } else {
        const float* xb = (const float*)x + b * Cc * HW + hw;
        #pragma unroll
        for (int c = 0; c < Cc; c++) xr[c] = xb[c * HW];
    }
    float s = 0.f, ss = 0.f;
    #pragma unroll
    for (int c = 0; c < Cc; c++) { s += xr[c]; ss += xr[c] * xr[c]; }
    float mu = s * (1.f / Cc);
    float var = ss * (1.f / Cc) - mu * mu;
    float r = rsqrtf(var + 1e-6f);
    #pragma unroll
    for (int c = 0; c < Cc; c++)
        xr[c] = wts[W_N2W + c] * ((xr[c] - mu) * r) + wts[W_N2B + c];

    int co0 = blockIdx.y * 24;
    for (int kq = 0; kq < 6; kq++) {
        float acc[4] = {0.f, 0.f, 0.f, 0.f};
        #pragma unroll
        for (int c = 0; c < Cc; c++) {
            float xv = xr[c];
            #pragma unroll
            for (int i = 0; i < 4; i++)
                acc[i] += wts[W_QKVW + (co0 + kq * 4 + i) * Cc + c] * xv;
        }
        #pragma unroll
        for (int i = 0; i < 4; i++)
            qkvr[(b * 144 + co0 + kq * 4 + i) * HW + hw] = acc[i];
    }
}

// ---------------- qkv depthwise 3x3: 4 px/thread float4. grid (16, 144) ----------------
__global__ void __launch_bounds__(256) k_qkvdw(const float* __restrict__ qkvr, const float* __restrict__ wts,
                        float* __restrict__ qkv) {
    int ch = blockIdx.y;   // 0..143
    const float* wk = wts + W_QKVDW + ch * 9;
    int pbase = blockIdx.x * 1024 + threadIdx.x * 4;
    int b = pbase >> 12, hw = pbase & 4095, h = hw >> 6, w0 = hw & 63;
    const float* plane = qkvr + (b * 144 + ch) * HW;

    float a0 = 0.f, a1 = 0.f, a2 = 0.f, a3 = 0.f;
    #pragma unroll
    for (int ki = 0; ki < 3; ki++) {
        int hh = h + ki - 1;
        if ((unsigned)hh < 64u) {
            const float* row = plane + hh * 64 + w0;
            float4 m = *(const float4*)row;
            float lf = (w0 > 0) ? row[-1] : 0.f;
            float rt = (w0 < 60) ? row[4] : 0.f;
            float k0 = wk[ki * 3], k1 = wk[ki * 3 + 1], k2 = wk[ki * 3 + 2];
            a0 += k0 * lf  + k1 * m.x + k2 * m.y;
            a1 += k0 * m.x + k1 * m.y + k2 * m.z;
            a2 += k0 * m.y + k1 * m.z + k2 * m.w;
            a3 += k0 * m.z + k1 * m.w + k2 * rt;
        }
    }
    float4 o; o.x = a0; o.y = a1; o.z = a2; o.w = a3;
    *(float4*)(qkv + (b * 144 + ch) * HW + hw) = o;
}

// ---------------- S partials + q/k norm partials: grid (32 bh, 16 chunks) x 256 ----------------
__global__ void k_smat1(const float* __restrict__ qkv, float* __restrict__ Sp) {
    int bh = blockIdx.x, chunk = blockIdx.y;
    int b = bh / HEADS, hd = bh % HEADS;
    const float* qb = qkv + (b * 144 + hd * CPH) * HW;
    const float* kb = qkv + (b * 144 + 48 + hd * CPH) * HW;
    int px = chunk * 256 + threadIdx.x;
    float qv[CPH], kv[CPH];
    #pragma unroll
    for (int c = 0; c < CPH; c++) { qv[c] = qb[c * HW + px]; kv[c] = kb[c * HW + px]; }
    float acc[48];
    #pragma unroll
    for (int c = 0; c < CPH; c++) {
        #pragma unroll
        for (int d = 0; d < CPH; d++) acc[c * CPH + d] = qv[c] * kv[d];
        acc[36 + c] = qv[c] * qv[c];
        acc[42 + c] = kv[c] * kv[c];
    }
    __shared__ float red[48 * 4];
    int lane = threadIdx.x & 63, wv = threadIdx.x >> 6;
    #pragma unroll
    for (int t = 0; t < 48; t++) {
        float v = acc[t];
        #pragma unroll
        for (int o = 32; o > 0; o >>= 1) v += __shfl_down(v, o);
        if (lane == 0) red[t * 4 + wv] = v;
    }
    __syncthreads();
    if (threadIdx.x < 48)
        Sp[(bh * 16 + chunk) * 48 + threadIdx.x] =
            red[threadIdx.x * 4] + red[threadIdx.x * 4 + 1] +
            red[threadIdx.x * 4 + 2] + red[threadIdx.x * 4 + 3];
}

// ---------------- finalize softmax S (+ channel attention ca1/ca2) ----------------
__global__ void k_smat2(const float* __restrict__ Sp, const float* __restrict__ gap,
                        const float* __restrict__ wts, float* __restrict__ S,
                        float* __restrict__ ca1, float* __restrict__ ca2) {
    int bh = blockIdx.x;
    int b = bh / HEADS, hd = bh % HEADS;
    int t = threadIdx.x;   // 64 threads
    __shared__ float sm[48];
    if (t < 48) {
        float v = 0.f;
        #pragma unroll
        for (int ch = 0; ch < 16; ch++) v += Sp[(bh * 16 + ch) * 48 + t];
        sm[t] = v;
    }
    __syncthreads();
    if (t < CPH) {
        float rqv = 1.f / fmaxf(sqrtf(sm[36 + t]), 1e-12f);
        float tmp = wts[W_TEMP + hd];
        float row[CPH];
        #pragma unroll
        for (int d = 0; d < CPH; d++) {
            float rkv = 1.f / fmaxf(sqrtf(sm[42 + d]), 1e-12f);
            row[d] = sm[t * CPH + d] * rqv * rkv * tmp;
        }
        float mx = row[0];
        #pragma unroll
        for (int d = 1; d < CPH; d++) mx = fmaxf(mx, row[d]);
        float sum = 0.f;
        #pragma unroll
        for (int d = 0; d < CPH; d++) { row[d] = expf(row[d] - mx); sum += row[d]; }
        float inv = 1.f / sum;
        #pragma unroll
        for (int d = 0; d < CPH; d++) S[bh * 36 + t * CPH + d] = row[d] * inv;
    }
    if (t >= 52 && t < 64) {
        int idx = t - 52;
        int which = idx / 6, cc = idx % 6;
        int co = hd * CPH + cc;
        const float* g = gap + b * Cc;
        float sacc = wts[(which ? W_CA2B : W_CA1B) + co];
        #pragma unroll
        for (int c = 0; c < Cc; c++)
            sacc += wts[(which ? W_CA2W : W_CA1W) + co * Cc + c] * g[c];
        (which ? ca2 : ca1)[b * Cc + co] = sacc;
    }
}

// ---------------- attn out: mdta = S @ v. grid (64, 8) ----------------
__global__ void __launch_bounds__(256) k_attout(const float* __restrict__ qkv, const float* __restrict__ S,
                         float* __restrict__ mdta) {
    int p = blockIdx.x * 256 + threadIdx.x;
    int b = p >> 12, hw = p & 4095;
    int hd = blockIdx.y;
    const float* vb = qkv + (b * 144 + 96 + hd * CPH) * HW + hw;
    float vv[CPH];
    #pragma unroll
    for (int d = 0; d < CPH; d++) vv[d] = vb[d * HW];
    const float* Sb = S + (b * HEADS + hd) * 36;
    #pragma unroll
    for (int c = 0; c < CPH; c++) {
        float acc = 0.f;
        #pragma unroll
        for (int d = 0; d < CPH; d++) acc += Sb[c * CPH + d] * vv[d];
        mdta[(b * Cc + hd * CPH + c) * HW + hw] = acc;
    }
}

// ---------------- final: out = x + kba*ca1 + mproj(mdta)*ca2. grid (64, 4) ----------------
__global__ void __launch_bounds__(256) k_final(const void* __restrict__ x, const uint32_t* __restrict__ n1w_raw,
                        const float* __restrict__ kba, const float* __restrict__ mdta,
                        const float* __restrict__ wts, const float* __restrict__ ca1,
                        const float* __restrict__ ca2, void* __restrict__ out) {
    int fl = dtype_bf16(n1w_raw);
    int p = blockIdx.x * 256 + threadIdx.x;
    int b = p >> 12, hw = p & 4095;
    const float* mb = mdta + b * Cc * HW + hw;
    int co0 = blockIdx.y * 12;
    float acc[12];
    #pragma unroll
    for (int k = 0; k < 12; k++) acc[k] = 0.f;
    for (int c = 0; c < Cc; c++) {
        float mv = mb[c * HW];
        #pragma unroll
        for (int k = 0; k < 12; k++)
            acc[k] += wts[W_MPROJ + (co0 + k) * Cc + c] * mv;
    }
    #pragma unroll
    for (int k = 0; k < 12; k++) {
        int co = co0 + k;
        int idx = (b * Cc + co) * HW + hw;
        float xv = fl ? b2f(((const ushortT*)x)[idx]) : ((const float*)x)[idx];
        float res = xv + kba[idx] * ca1[b * Cc + co] + acc[k] * ca2[b * Cc + co];
        if (fl) ((ushortT*)out)[idx] = f2b(res);
        else    ((float*)out)[idx] = res;
    }
}

// ---------------- host launch ----------------
extern "C" void kernel_launch(void* const* d_in, const int* in_sizes, int n_in,
                              void* d_out, int out_size, void* d_ws, size_t ws_size,
                              hipStream_t stream) {
    float* ws_f = (float*)d_ws;

    float* xn    = ws_f + FXN;    // later mdta
    float* bufA  = ws_f + FA;     // t1 -> hbuf -> qkvr -> Sp
    float* bufB  = ws_f + FB;     // t2
    float* bufC  = ws_f + FC;     // x1g -> qkv
    float* bufD  = ws_f + FD;     // uf
    float* araw  = ws_f + FARAW;
    float* attn_t= ws_f + FATT;
    float* kba   = ws_f + FKBA;
    float* gap   = ws_f + FGAP;
    float* ca1   = ws_f + FCA1;
    float* ca2   = ws_f + FCA2;
    float* Smat  = ws_f + FS;
    float* wts   = ws_f + FW;
    ushortT* att_bf = (ushortT*)(ws_f + FATTB);
    ushortT* Wt     = (ushortT*)(ws_f + FWT);

    float* qkvr = bufA;
    float* qkv  = bufC;
    float* Sp   = bufA;
    float* mdta = xn;
    const uint32_t* n1w_raw = (const uint32_t*)d_in[1];

    static const int wsizes[27] = {48,48,48,48,4608,864,4608,864,4608,432,24,384,32,
                                   1536,32,110592,3072,32,96,8,6912,1296,2304,2304,48,2304,48};
    static const int woffs[27] = {W_N1W,W_N1B,W_N2W,W_N2B,W_KDW1,W_KDW2,W_KC1A,W_KC1B,
                                  W_KPROJ,W_C2AW,W_C2AB,W_C2BW,W_C2BB,W_C211W,W_C211B,
                                  W_KW,W_KB,W_ATTG,W_GA1,W_TEMP,W_QKVW,W_QKVDW,W_MPROJ,
                                  W_CA1W,W_CA1B,W_CA2W,W_CA2B};
    ConvPack cp;
    for (int i = 0; i < 27; i++) {
        cp.src[i] = d_in[i + 1];
        cp.dstoff[i] = woffs[i];
        cp.n[i] = wsizes[i];
    }

    k_prep<<<dim3(64, 29), 256, 0, stream>>>(cp, wts, Wt, d_in[0], gap,
                                             d_in[16], d_in[17], n1w_raw);
    k_pw1<<<dim3(64, 8), 256, 0, stream>>>(d_in[0], n1w_raw, wts, xn, bufA, bufB, attn_t);
    k_dw<<<dim3(16, 216), 256, 0, stream>>>(bufA, bufB, xn, wts, bufC, bufD, araw);
    k_att<<<dim3(64), 256, 0, stream>>>(araw, attn_t, wts, att_bf);
    k_kba<<<dim3(64, 24), 256, 0, stream>>>(att_bf, bufD, bufC, Wt, wts, bufA);
    k_kproj<<<dim3(64, 8), 256, 0, stream>>>(bufA, wts, kba);
    k_qkvpw<<<dim3(64, 6), 256, 0, stream>>>(d_in[0], n1w_raw, wts, qkvr);
    k_qkvdw<<<dim3(16, 144), 256, 0, stream>>>(qkvr, wts, qkv);
    k_smat1<<<dim3(32, 16), 256, 0, stream>>>(qkv, Sp);
    k_smat2<<<dim3(32), 64, 0, stream>>>(Sp, gap, wts, Smat, ca1, ca2);
    k_attout<<<dim3(64, 8), 256, 0, stream>>>(qkv, Smat, mdta);
    k_final<<<dim3(64, 4), 256, 0, stream>>>(d_in[0], n1w_raw, kba, mdta, wts, ca1, ca2, d_out);
}

// Round 7
// 225.432 us; speedup vs baseline: 1.5285x; 1.2340x over previous
//
#include <hip/hip_runtime.h>
#include <hip/hip_bf16.h>
#include <cstdint>

typedef unsigned short ushortT;
typedef __attribute__((ext_vector_type(8))) short short8;
typedef __attribute__((ext_vector_type(4))) float f32x4;

// ---------------- problem constants ----------------
static constexpr int Bn = 4, Cc = 48, Hh = 64, Wd = 64, HW = 4096;
static constexpr int HID = 96, NSET = 32, INTERC = 24, HEADS = 8, CPH = 6;

// ---------------- ws layout (float offsets) ----------------
static constexpr int FXN   = 0;         // 786432  xn fp32 planar (c2a halo use)
static constexpr int FA    = 786432;    // 1572864 t1 -> qkvr(spans A+B) -> Sp
static constexpr int FB    = 2359296;   // 1572864 t2
static constexpr int FC    = 3932160;   // 1572864 x1g -> qkv (spans C+D)
static constexpr int FD    = 5505024;   // 1572864 uf
static constexpr int FARAW = 7077888;   // 393216
static constexpr int FATT  = 7471104;   // 524288  attn_t fp32 [p][32]
static constexpr int FKBA  = 7995392;   // 786432  kba planar fp32
static constexpr int FGAP  = 8781824;   // 192
static constexpr int FCA1  = 8782016;   // 192
static constexpr int FCA2  = 8782208;   // 192
static constexpr int FS    = 8782400;   // 1152 Smat
static constexpr int FW    = 8783552;   // 147200 fp32 weights
static constexpr int FATTB = 8930752;   // 262144 fl: att_bf [p][32] bf16
static constexpr int FWT   = 9192896;   // 61440 fl: Wt bf16 (KBA)
static constexpr int FXNB  = 9254336;   // 524288 fl: xnb [p][64] bf16
static constexpr int FXMB  = 9778624;   // 524288 fl: xmb [p][64] bf16
static constexpr int FHBF  = 10302912;  // 786432 fl: h_bf [p][96] bf16
static constexpr int FMDB  = 11089344;  // 524288 fl: mdta_bf [p][64] bf16
static constexpr int FWPW  = 11613632;  // 7168 fl: Wpw [224][64] bf16
static constexpr int FWQK  = 11620800;  // 4608 fl: Wqk [144][64] bf16
static constexpr int FWKP  = 11625408;  // 2304 fl: Wkp [48][96] bf16
static constexpr int FWMP  = 11627712;  // 1536 fl: Wmp [48][64] bf16
// total = 11629248 floats = 46.5 MB

// ---- weight offsets inside FW ----
static constexpr int W_N1W=0, W_N1B=48, W_N2W=96, W_N2B=144;
static constexpr int W_KDW1=192, W_KDW2=4800, W_KC1A=5664, W_KC1B=10272;
static constexpr int W_KPROJ=11136, W_C2AW=15744, W_C2AB=16176;
static constexpr int W_C2BW=16200, W_C2BB=16584, W_C211W=16616, W_C211B=18152;
static constexpr int W_KW=18184, W_KB=128776, W_ATTG=131848, W_GA1=131880;
static constexpr int W_TEMP=131976, W_QKVW=131984, W_QKVDW=138896, W_MPROJ=140192;
static constexpr int W_CA1W=142496, W_CA1B=144800, W_CA2W=144848, W_CA2B=147152;

__device__ __forceinline__ float b2f(ushortT u) {
    union { uint32_t i; float f; } v; v.i = ((uint32_t)u) << 16; return v.f;
}
__device__ __forceinline__ ushortT f2b(float f) {
    union { float f; uint32_t i; } v; v.f = f;
    uint32_t i = v.i;
    uint32_t lsb = (i >> 16) & 1u;
    i += 0x7fffu + lsb;
    return (ushortT)(i >> 16);
}
__device__ __forceinline__ int dtype_bf16(const uint32_t* n1w_raw) {
    return n1w_raw[0] == 0x3F803F80u;
}
__device__ __forceinline__ ushortT raw_bf(const void* p, int idx, int fl) {
    return fl ? ((const ushortT*)p)[idx] : f2b(((const float*)p)[idx]);
}

// ---------------- prep ----------------
struct ConvPack {
    const void* src[27];
    int dstoff[27];
    int n[27];
};
struct RawW {
    const void* kdw1; const void* kc1a; const void* c211w; const void* qkvw;
    const void* kproj; const void* mproj; const void* kw; const void* kb;
};

__global__ void k_prep(ConvPack p, RawW rw, float* __restrict__ dst,
                       ushortT* __restrict__ Wt, ushortT* __restrict__ Wpw,
                       ushortT* __restrict__ Wqk, ushortT* __restrict__ Wkp,
                       ushortT* __restrict__ Wmp,
                       const void* __restrict__ x, float* __restrict__ gap,
                       const uint32_t* __restrict__ n1w_raw) {
    int fl = dtype_bf16(n1w_raw);
    int y = blockIdx.y;
    if (y < 27) {
        int n = p.n[y];
        for (int i = blockIdx.x * 256 + threadIdx.x; i < n; i += 64 * 256) {
            float v;
            if (fl) v = b2f(((const ushortT*)p.src[y])[i]);
            else    v = ((const float*)p.src[y])[i];
            dst[p.dstoff[y] + i] = v;
        }
    } else if (y == 27) {
        for (int u = blockIdx.x * 256 + threadIdx.x; u < 24 * 160 * 32; u += 64 * 256) {
            int n = u & 31;
            int rest = u >> 5;
            int r = rest % 160;
            int gr = rest / 160;
            ushortT out;
            if (r < 144) {
                int j = r >> 2, i = r & 3;
                out = raw_bf(rw.kw, n * 3456 + gr * 144 + i * 36 + j, fl);
            } else if (r < 148) {
                out = raw_bf(rw.kb, n * HID + gr * 4 + (r - 144), fl);
            } else out = 0;
            Wt[u] = out;
        }
    } else if (y == 28) {
        for (int u = blockIdx.x * 256 + threadIdx.x; u < 224 * 64; u += 64 * 256) {
            int co = u >> 6, c = u & 63;
            ushortT v = 0;
            if (c < 48) {
                if (co < 96)       v = raw_bf(rw.kdw1,  co * 48 + c, fl);
                else if (co < 192) v = raw_bf(rw.kc1a,  (co - 96) * 48 + c, fl);
                else               v = raw_bf(rw.c211w, (co - 192) * 48 + c, fl);
            }
            Wpw[u] = v;
        }
    } else if (y == 29) {
        for (int u = blockIdx.x * 256 + threadIdx.x; u < 144 * 64; u += 64 * 256) {
            int co = u >> 6, c = u & 63;
            Wqk[u] = (c < 48) ? raw_bf(rw.qkvw, co * 48 + c, fl) : (ushortT)0;
        }
    } else if (y == 30) {
        for (int u = blockIdx.x * 256 + threadIdx.x; u < 48 * 96; u += 64 * 256) {
            int co = u / 96, c = u % 96;
            Wkp[u] = raw_bf(rw.kproj, co * 96 + c, fl);
        }
    } else if (y == 31) {
        for (int u = blockIdx.x * 256 + threadIdx.x; u < 48 * 64; u += 64 * 256) {
            int co = u >> 6, c = u & 63;
            Wmp[u] = (c < 48) ? raw_bf(rw.mproj, co * 48 + c, fl) : (ushortT)0;
        }
    } else {
        __shared__ float red[4];
        for (int bc = blockIdx.x; bc < Bn * Cc; bc += 64) {
            float s = 0.f;
            if (fl) {
                const ushortT* xb = (const ushortT*)x + bc * HW;
                for (int i = threadIdx.x; i < HW; i += 256) s += b2f(xb[i]);
            } else {
                const float* xb = (const float*)x + bc * HW;
                for (int i = threadIdx.x; i < HW; i += 256) s += xb[i];
            }
            #pragma unroll
            for (int o = 32; o > 0; o >>= 1) s += __shfl_down(s, o);
            int lane = threadIdx.x & 63, wv = threadIdx.x >> 6;
            if (lane == 0) red[wv] = s;
            __syncthreads();
            if (threadIdx.x == 0)
                gap[bc] = (red[0] + red[1] + red[2] + red[3]) * (1.f / HW);
            __syncthreads();
        }
    }
}

// ---------------- LN1 + LN2 -> xnb/xmb [p][64] bf16 + xn fp32 planar. grid 256 x 64 ----------------
__global__ void __launch_bounds__(64) k_ln(const void* __restrict__ x, const uint32_t* __restrict__ n1w_raw,
                     const float* __restrict__ wts, float* __restrict__ xn,
                     ushortT* __restrict__ xnb, ushortT* __restrict__ xmb) {
    int fl = dtype_bf16(n1w_raw);
    int p = blockIdx.x * 64 + threadIdx.x;
    int b = p >> 12, hw = p & 4095;
    float xr[Cc];
    if (fl) {
        const ushortT* xb = (const ushortT*)x + b * Cc * HW + hw;
        #pragma unroll
        for (int c = 0; c < Cc; c++) xr[c] = b2f(xb[c * HW]);
    } else {
        const float* xb = (const float*)x + b * Cc * HW + hw;
        #pragma unroll
        for (int c = 0; c < Cc; c++) xr[c] = xb[c * HW];
    }
    float s = 0.f, ss = 0.f;
    #pragma unroll
    for (int c = 0; c < Cc; c++) { s += xr[c]; ss += xr[c] * xr[c]; }
    float mu = s * (1.f / Cc);
    float var = ss * (1.f / Cc) - mu * mu;
    float r = rsqrtf(var + 1e-6f);
    uint32_t pn[32], pm[32];
    #pragma unroll
    for (int i = 0; i < 24; i++) {
        float y0 = (xr[2 * i] - mu) * r, y1 = (xr[2 * i + 1] - mu) * r;
        float n0 = wts[W_N1W + 2 * i] * y0 + wts[W_N1B + 2 * i];
        float n1 = wts[W_N1W + 2 * i + 1] * y1 + wts[W_N1B + 2 * i + 1];
        float m0 = wts[W_N2W + 2 * i] * y0 + wts[W_N2B + 2 * i];
        float m1 = wts[W_N2W + 2 * i + 1] * y1 + wts[W_N2B + 2 * i + 1];
        xn[(b * Cc + 2 * i) * HW + hw] = n0;
        xn[(b * Cc + 2 * i + 1) * HW + hw] = n1;
        pn[i] = (uint32_t)f2b(n0) | ((uint32_t)f2b(n1) << 16);
        pm[i] = (uint32_t)f2b(m0) | ((uint32_t)f2b(m1) << 16);
    }
    #pragma unroll
    for (int i = 24; i < 32; i++) { pn[i] = 0; pm[i] = 0; }
    uint4* dn = (uint4*)(xnb + (size_t)p * 64);
    uint4* dm = (uint4*)(xmb + (size_t)p * 64);
    #pragma unroll
    for (int qd = 0; qd < 8; qd++) {
        uint4 v; v.x = pn[qd*4]; v.y = pn[qd*4+1]; v.z = pn[qd*4+2]; v.w = pn[qd*4+3];
        dn[qd] = v;
        uint4 u; u.x = pm[qd*4]; u.y = pm[qd*4+1]; u.z = pm[qd*4+2]; u.w = pm[qd*4+3];
        dm[qd] = u;
    }
}

// ---------------- pw1 via MFMA: [224 x 48] @ xnb -> t1,t2 planar + attn_t. grid 256 x 256 ----------------
__global__ void __launch_bounds__(256) k_pw1m(const ushortT* __restrict__ xnb, const ushortT* __restrict__ Wpw,
                       const float* __restrict__ wts, float* __restrict__ t1,
                       float* __restrict__ t2, float* __restrict__ attn_t) {
    int wave = threadIdx.x >> 6, lane = threadIdx.x & 63;
    int m = lane & 15, q = lane >> 4;
    int p = blockIdx.x * 64 + wave * 16 + m;
    int b = p >> 12, hw = p & 4095;
    short8 B0 = *(const short8*)(xnb + (size_t)p * 64 + q * 8);
    short8 B1 = *(const short8*)(xnb + (size_t)p * 64 + 32 + q * 8);
    #pragma unroll
    for (int t = 0; t < 14; t++) {
        short8 A0 = *(const short8*)(Wpw + (16 * t + m) * 64 + q * 8);
        short8 A1 = *(const short8*)(Wpw + (16 * t + m) * 64 + 32 + q * 8);
        f32x4 z = {0.f, 0.f, 0.f, 0.f};
        f32x4 D = __builtin_amdgcn_mfma_f32_16x16x32_bf16(A0, B0, z, 0, 0, 0);
        D = __builtin_amdgcn_mfma_f32_16x16x32_bf16(A1, B1, D, 0, 0, 0);
        #pragma unroll
        for (int g = 0; g < 4; g++) {
            int co = 16 * t + 4 * q + g;
            if (t < 6) t1[(b * HID + co) * HW + hw] = D[g];
            else if (t < 12) t2[(b * HID + (co - 96)) * HW + hw] = D[g];
            else {
                int n = co - 192;
                attn_t[(size_t)p * 32 + n] = D[g] + wts[W_C211B + n];
            }
        }
    }
}

// ---------------- depthwise/grouped 3x3: 4 px/thread float4. grid (16, 216) ----------------
__global__ void __launch_bounds__(256) k_dw(const float* __restrict__ t1, const float* __restrict__ t2,
                     const float* __restrict__ xn, const float* __restrict__ wts,
                     float* __restrict__ x1g, float* __restrict__ uf, float* __restrict__ araw) {
    int y = blockIdx.y;
    int pbase = blockIdx.x * 1024 + threadIdx.x * 4;
    int b = pbase >> 12, hw = pbase & 4095, h = hw >> 6, w0 = hw & 63;

    if (y < 192) {
        int c = (y < 96) ? y : y - 96;
        const float* base = (y < 96) ? t1 : t2;
        const float* wk = wts + ((y < 96) ? W_KDW2 : W_KC1B) + c * 9;
        const float* plane = base + (b * HID + c) * HW;

        float a0 = 0.f, a1 = 0.f, a2 = 0.f, a3 = 0.f;
        #pragma unroll
        for (int ki = 0; ki < 3; ki++) {
            int hh = h + ki - 1;
            if ((unsigned)hh < 64u) {
                const float* row = plane + hh * 64 + w0;
                float4 mm = *(const float4*)row;
                float lf = (w0 > 0) ? row[-1] : 0.f;
                float rt = (w0 < 60) ? row[4] : 0.f;
                float k0 = wk[ki * 3], k1 = wk[ki * 3 + 1], k2 = wk[ki * 3 + 2];
                a0 += k0 * lf   + k1 * mm.x + k2 * mm.y;
                a1 += k0 * mm.x + k1 * mm.y + k2 * mm.z;
                a2 += k0 * mm.y + k1 * mm.z + k2 * mm.w;
                a3 += k0 * mm.z + k1 * mm.w + k2 * rt;
            }
        }
        int idx = (b * HID + c) * HW + hw;
        if (y < 96) {
            float4 g;
            g.x = 0.5f * a0 * (1.f + erff(a0 * 0.70710678118654752f));
            g.y = 0.5f * a1 * (1.f + erff(a1 * 0.70710678118654752f));
            g.z = 0.5f * a2 * (1.f + erff(a2 * 0.70710678118654752f));
            g.w = 0.5f * a3 * (1.f + erff(a3 * 0.70710678118654752f));
            *(float4*)(x1g + idx) = g;
        } else {
            float4 o; o.x = a0; o.y = a1; o.z = a2; o.w = a3;
            *(float4*)(uf + idx) = o;
        }
    } else {
        int o = y - 192;
        float bias = wts[W_C2AB + o];
        float a0 = bias, a1 = bias, a2 = bias, a3 = bias;
        #pragma unroll
        for (int ic = 0; ic < 2; ic++) {
            const float* plane = xn + (b * Cc + 2 * o + ic) * HW;
            const float* wk = wts + W_C2AW + (o * 2 + ic) * 9;
            #pragma unroll
            for (int ki = 0; ki < 3; ki++) {
                int hh = h + ki - 1;
                if ((unsigned)hh < 64u) {
                    const float* row = plane + hh * 64 + w0;
                    float4 mm = *(const float4*)row;
                    float lf = (w0 > 0) ? row[-1] : 0.f;
                    float rt = (w0 < 60) ? row[4] : 0.f;
                    float k0 = wk[ki * 3], k1 = wk[ki * 3 + 1], k2 = wk[ki * 3 + 2];
                    a0 += k0 * lf   + k1 * mm.x + k2 * mm.y;
                    a1 += k0 * mm.x + k1 * mm.y + k2 * mm.z;
                    a2 += k0 * mm.y + k1 * mm.z + k2 * mm.w;
                    a3 += k0 * mm.z + k1 * mm.w + k2 * rt;
                }
            }
        }
        float4 out; out.x = a0; out.y = a1; out.z = a2; out.w = a3;
        *(float4*)(araw + (b * INTERC + o) * HW + hw) = out;
    }
}

// ---------------- att = attgamma * c2b(SimpleGate(araw)) + attn_t -> bf16 [p][32]. grid 64 x 256 ----------------
__global__ void __launch_bounds__(256) k_att(const float* __restrict__ araw, const float* __restrict__ attn_t,
                     const float* __restrict__ wts, ushortT* __restrict__ att_bf) {
    int p = blockIdx.x * 256 + threadIdx.x;
    int b = p >> 12, hw = p & 4095;
    const float* ab = araw + b * INTERC * HW + hw;
    float sg[12];
    #pragma unroll
    for (int i = 0; i < 12; i++) sg[i] = ab[i * HW] * ab[(12 + i) * HW];
    const float* ct = attn_t + (size_t)p * 32;
    uint32_t packed[16];
    #pragma unroll
    for (int nq = 0; nq < 16; nq++) {
        float v2[2];
        #pragma unroll
        for (int u = 0; u < 2; u++) {
            int n = nq * 2 + u;
            float a = wts[W_C2BB + n];
            #pragma unroll
            for (int c = 0; c < 12; c++) a += wts[W_C2BW + n * 12 + c] * sg[c];
            v2[u] = wts[W_ATTG + n] * a + ct[n];
        }
        packed[nq] = (uint32_t)f2b(v2[0]) | ((uint32_t)f2b(v2[1]) << 16);
    }
    uint4* dst = (uint4*)(att_bf + (size_t)p * 32);
    #pragma unroll
    for (int q = 0; q < 4; q++) {
        uint4 v; v.x = packed[q*4]; v.y = packed[q*4+1]; v.z = packed[q*4+2]; v.w = packed[q*4+3];
        dst[q] = v;
    }
}

// ---------------- KBA core via MFMA -> h_bf [p][96] bf16. grid (64,24) x 256 ----------------
__global__ void __launch_bounds__(256) k_kba(const ushortT* __restrict__ att_bf, const float* __restrict__ uf,
                     const float* __restrict__ x1g, const ushortT* __restrict__ Wt,
                     const float* __restrict__ wts, ushortT* __restrict__ h_bf) {
    int wave = threadIdx.x >> 6, lane = threadIdx.x & 63;
    int m = lane & 15, q = lane >> 4;
    int gr = blockIdx.y;

    short8 A[10];
    const ushortT* wtg = Wt + gr * 160 * 32;
    #pragma unroll
    for (int t = 0; t < 10; t++)
        A[t] = *(const short8*)(wtg + (16 * t + m) * 32 + q * 8);

    for (int tile = 0; tile < 4; tile++) {
        int p = blockIdx.x * 256 + wave * 64 + tile * 16 + m;
        int b = p >> 12, hw = p & 4095, h = hw >> 6, w = hw & 63;

        short8 Bf = *(const short8*)(att_bf + (size_t)p * 32 + q * 8);

        f32x4 D[10];
        #pragma unroll
        for (int t = 0; t < 10; t++) {
            f32x4 z = {0.f, 0.f, 0.f, 0.f};
            D[t] = __builtin_amdgcn_mfma_f32_16x16x32_bf16(A[t], Bf, z, 0, 0, 0);
        }

        float s0 = 0.f, s1 = 0.f, s2 = 0.f, s3 = 0.f;
        #pragma unroll
        for (int t = 0; t < 9; t++) {
            int j = 4 * t + q;
            int ci = j / 9;
            int kk = j - 9 * ci;
            int ki = kk / 3, kj = kk - 3 * ki;
            int hh = h + ki - 1, ww = w + kj - 1;
            float tap = 0.f;
            if ((unsigned)hh < 64u && (unsigned)ww < 64u)
                tap = uf[(b * HID + gr * 4 + ci) * HW + hh * 64 + ww];
            s0 += D[t][0] * tap;
            s1 += D[t][1] * tap;
            s2 += D[t][2] * tap;
            s3 += D[t][3] * tap;
        }
        s0 += D[9][0]; s1 += D[9][1]; s2 += D[9][2]; s3 += D[9][3];

        s0 += __shfl_xor(s0, 16); s0 += __shfl_xor(s0, 32);
        s1 += __shfl_xor(s1, 16); s1 += __shfl_xor(s1, 32);
        s2 += __shfl_xor(s2, 16); s2 += __shfl_xor(s2, 32);
        s3 += __shfl_xor(s3, 16); s3 += __shfl_xor(s3, 32);

        float sel = (q == 0) ? s0 : ((q == 1) ? s1 : ((q == 2) ? s2 : s3));
        int ch = gr * 4 + q;
        int idx = (b * HID + ch) * HW + hw;
        float x2 = sel * wts[W_GA1 + ch] + uf[idx];
        float hv = x1g[idx] * x2;
        h_bf[(size_t)p * 96 + ch] = f2b(hv);
    }
}

// ---------------- kproj via MFMA: [48 x 96] @ h_bf -> kba planar. grid 256 x 256 ----------------
__global__ void __launch_bounds__(256) k_kprojm(const ushortT* __restrict__ h_bf, const ushortT* __restrict__ Wkp,
                        float* __restrict__ kba) {
    int wave = threadIdx.x >> 6, lane = threadIdx.x & 63;
    int m = lane & 15, q = lane >> 4;
    int p = blockIdx.x * 64 + wave * 16 + m;
    int b = p >> 12, hw = p & 4095;
    short8 B0 = *(const short8*)(h_bf + (size_t)p * 96 + q * 8);
    short8 B1 = *(const short8*)(h_bf + (size_t)p * 96 + 32 + q * 8);
    short8 B2 = *(const short8*)(h_bf + (size_t)p * 96 + 64 + q * 8);
    #pragma unroll
    for (int t = 0; t < 3; t++) {
        short8 A0 = *(const short8*)(Wkp + (16 * t + m) * 96 + q * 8);
        short8 A1 = *(const short8*)(Wkp + (16 * t + m) * 96 + 32 + q * 8);
        short8 A2 = *(const short8*)(Wkp + (16 * t + m) * 96 + 64 + q * 8);
        f32x4 z = {0.f, 0.f, 0.f, 0.f};
        f32x4 D = __builtin_amdgcn_mfma_f32_16x16x32_bf16(A0, B0, z, 0, 0, 0);
        D = __builtin_amdgcn_mfma_f32_16x16x32_bf16(A1, B1, D, 0, 0, 0);
        D = __builtin_amdgcn_mfma_f32_16x16x32_bf16(A2, B2, D, 0, 0, 0);
        #pragma unroll
        for (int g = 0; g < 4; g++) {
            int co = 16 * t + 4 * q + g;
            kba[(b * Cc + co) * HW + hw] = D[g];
        }
    }
}

// ---------------- qkv pointwise via MFMA: [144 x 48] @ xmb -> qkvr planar. grid 256 x 256 ----------------
__global__ void __launch_bounds__(256) k_qkvpwm(const ushortT* __restrict__ xmb, const ushortT* __restrict__ Wqk,
                        float* __restrict__ qkvr) {
    int wave = threadIdx.x >> 6, lane = threadIdx.x & 63;
    int m = lane & 15, q = lane >> 4;
    int p = blockIdx.x * 64 + wave * 16 + m;
    int b = p >> 12, hw = p & 4095;
    short8 B0 = *(const short8*)(xmb + (size_t)p * 64 + q * 8);
    short8 B1 = *(const short8*)(xmb + (size_t)p * 64 + 32 + q * 8);
    #pragma unroll
    for (int t = 0; t < 9; t++) {
        short8 A0 = *(const short8*)(Wqk + (16 * t + m) * 64 + q * 8);
        short8 A1 = *(const short8*)(Wqk + (16 * t + m) * 64 + 32 + q * 8);
        f32x4 z = {0.f, 0.f, 0.f, 0.f};
        f32x4 D = __builtin_amdgcn_mfma_f32_16x16x32_bf16(A0, B0, z, 0, 0, 0);
        D = __builtin_amdgcn_mfma_f32_16x16x32_bf16(A1, B1, D, 0, 0, 0);
        #pragma unroll
        for (int g = 0; g < 4; g++) {
            int co = 16 * t + 4 * q + g;
            qkvr[(b * 144 + co) * HW + hw] = D[g];
        }
    }
}

// ---------------- qkv depthwise 3x3: 4 px/thread float4. grid (16, 144) ----------------
__global__ void __launch_bounds__(256) k_qkvdw(const float* __restrict__ qkvr, const float* __restrict__ wts,
                        float* __restrict__ qkv) {
    int ch = blockIdx.y;
    const float* wk = wts + W_QKVDW + ch * 9;
    int pbase = blockIdx.x * 1024 + threadIdx.x * 4;
    int b = pbase >> 12, hw = pbase & 4095, h = hw >> 6, w0 = hw & 63;
    const float* plane = qkvr + (b * 144 + ch) * HW;

    float a0 = 0.f, a1 = 0.f, a2 = 0.f, a3 = 0.f;
    #pragma unroll
    for (int ki = 0; ki < 3; ki++) {
        int hh = h + ki - 1;
        if ((unsigned)hh < 64u) {
            const float* row = plane + hh * 64 + w0;
            float4 mm = *(const float4*)row;
            float lf = (w0 > 0) ? row[-1] : 0.f;
            float rt = (w0 < 60) ? row[4] : 0.f;
            float k0 = wk[ki * 3], k1 = wk[ki * 3 + 1], k2 = wk[ki * 3 + 2];
            a0 += k0 * lf   + k1 * mm.x + k2 * mm.y;
            a1 += k0 * mm.x + k1 * mm.y + k2 * mm.z;
            a2 += k0 * mm.y + k1 * mm.z + k2 * mm.w;
            a3 += k0 * mm.z + k1 * mm.w + k2 * rt;
        }
    }
    float4 o; o.x = a0; o.y = a1; o.z = a2; o.w = a3;
    *(float4*)(qkv + (b * 144 + ch) * HW + hw) = o;
}

// ---------------- S partials + q/k norm partials: grid (32, 16) x 256 ----------------
__global__ void k_smat1(const float* __restrict__ qkv, float* __restrict__ Sp) {
    int bh = blockIdx.x, chunk = blockIdx.y;
    int b = bh / HEADS, hd = bh % HEADS;
    const float* qb = qkv + (b * 144 + hd * CPH) * HW;
    const float* kb = qkv + (b * 144 + 48 + hd * CPH) * HW;
    int px = chunk * 256 + threadIdx.x;
    float qv[CPH], kv[CPH];
    #pragma unroll
    for (int c = 0; c < CPH; c++) { qv[c] = qb[c * HW + px]; kv[c] = kb[c * HW + px]; }
    float acc[48];
    #pragma unroll
    for (int c = 0; c < CPH; c++) {
        #pragma unroll
        for (int d = 0; d < CPH; d++) acc[c * CPH + d] = qv[c] * kv[d];
        acc[36 + c] = qv[c] * qv[c];
        acc[42 + c] = kv[c] * kv[c];
    }
    __shared__ float red[48 * 4];
    int lane = threadIdx.x & 63, wv = threadIdx.x >> 6;
    #pragma unroll
    for (int t = 0; t < 48; t++) {
        float v = acc[t];
        #pragma unroll
        for (int o = 32; o > 0; o >>= 1) v += __shfl_down(v, o);
        if (lane == 0) red[t * 4 + wv] = v;
    }
    __syncthreads();
    if (threadIdx.x < 48)
        Sp[(bh * 16 + chunk) * 48 + threadIdx.x] =
            red[threadIdx.x * 4] + red[threadIdx.x * 4 + 1] +
            red[threadIdx.x * 4 + 2] + red[threadIdx.x * 4 + 3];
}

// ---------------- finalize softmax S (+ channel attention ca1/ca2) ----------------
__global__ void k_smat2(const float* __restrict__ Sp, const float* __restrict__ gap,
                        const float* __restrict__ wts, float* __restrict__ S,
                        float* __restrict__ ca1, float* __restrict__ ca2) {
    int bh = blockIdx.x;
    int b = bh / HEADS, hd = bh % HEADS;
    int t = threadIdx.x;
    __shared__ float sm[48];
    if (t < 48) {
        float v = 0.f;
        #pragma unroll
        for (int ch = 0; ch < 16; ch++) v += Sp[(bh * 16 + ch) * 48 + t];
        sm[t] = v;
    }
    __syncthreads();
    if (t < CPH) {
        float rqv = 1.f / fmaxf(sqrtf(sm[36 + t]), 1e-12f);
        float tmp = wts[W_TEMP + hd];
        float row[CPH];
        #pragma unroll
        for (int d = 0; d < CPH; d++) {
            float rkv = 1.f / fmaxf(sqrtf(sm[42 + d]), 1e-12f);
            row[d] = sm[t * CPH + d] * rqv * rkv * tmp;
        }
        float mx = row[0];
        #pragma unroll
        for (int d = 1; d < CPH; d++) mx = fmaxf(mx, row[d]);
        float sum = 0.f;
        #pragma unroll
        for (int d = 0; d < CPH; d++) { row[d] = expf(row[d] - mx); sum += row[d]; }
        float inv = 1.f / sum;
        #pragma unroll
        for (int d = 0; d < CPH; d++) S[bh * 36 + t * CPH + d] = row[d] * inv;
    }
    if (t >= 52 && t < 64) {
        int idx = t - 52;
        int which = idx / 6, cc = idx % 6;
        int co = hd * CPH + cc;
        const float* g = gap + b * Cc;
        float sacc = wts[(which ? W_CA2B : W_CA1B) + co];
        #pragma unroll
        for (int c = 0; c < Cc; c++)
            sacc += wts[(which ? W_CA2W : W_CA1W) + co * Cc + c] * g[c];
        (which ? ca2 : ca1)[b * Cc + co] = sacc;
    }
}

// ---------------- attn out: mdta = S @ v -> mdta_bf [p][64] bf16. grid (64, 8) ----------------
__global__ void __launch_bounds__(256) k_attout(const float* __restrict__ qkv, const float* __restrict__ S,
                         ushortT* __restrict__ mdta_bf) {
    int p = blockIdx.x * 256 + threadIdx.x;
    int b = p >> 12, hw = p & 4095;
    int hd = blockIdx.y;
    const float* vb = qkv + (b * 144 + 96 + hd * CPH) * HW + hw;
    float vv[CPH];
    #pragma unroll
    for (int d = 0; d < CPH; d++) vv[d] = vb[d * HW];
    const float* Sb = S + (b * HEADS + hd) * 36;
    float acc[CPH];
    #pragma unroll
    for (int c = 0; c < CPH; c++) {
        float a = 0.f;
        #pragma unroll
        for (int d = 0; d < CPH; d++) a += Sb[c * CPH + d] * vv[d];
        acc[c] = a;
    }
    uint32_t* dst = (uint32_t*)mdta_bf + (size_t)p * 32 + hd * 3;
    dst[0] = (uint32_t)f2b(acc[0]) | ((uint32_t)f2b(acc[1]) << 16);
    dst[1] = (uint32_t)f2b(acc[2]) | ((uint32_t)f2b(acc[3]) << 16);
    dst[2] = (uint32_t)f2b(acc[4]) | ((uint32_t)f2b(acc[5]) << 16);
    if (hd == 0) {
        uint32_t* pz = (uint32_t*)mdta_bf + (size_t)p * 32 + 24;
        #pragma unroll
        for (int i = 0; i < 8; i++) pz[i] = 0;
    }
}

// ---------------- final via MFMA: [48 x 48] @ mdta_bf, epilogue residual. grid 256 x 256 ----------------
__global__ void __launch_bounds__(256) k_finalm(const void* __restrict__ x, const uint32_t* __restrict__ n1w_raw,
                        const ushortT* __restrict__ mdta_bf, const ushortT* __restrict__ Wmp,
                        const float* __restrict__ kba, const float* __restrict__ ca1,
                        const float* __restrict__ ca2, void* __restrict__ out) {
    int fl = dtype_bf16(n1w_raw);
    int wave = threadIdx.x >> 6, lane = threadIdx.x & 63;
    int m = lane & 15, q = lane >> 4;
    int p = blockIdx.x * 64 + wave * 16 + m;
    int b = p >> 12, hw = p & 4095;
    short8 B0 = *(const short8*)(mdta_bf + (size_t)p * 64 + q * 8);
    short8 B1 = *(const short8*)(mdta_bf + (size_t)p * 64 + 32 + q * 8);
    #pragma unroll
    for (int t = 0; t < 3; t++) {
        short8 A0 = *(const short8*)(Wmp + (16 * t + m) * 64 + q * 8);
        short8 A1 = *(const short8*)(Wmp + (16 * t + m) * 64 + 32 + q * 8);
        f32x4 z = {0.f, 0.f, 0.f, 0.f};
        f32x4 D = __builtin_amdgcn_mfma_f32_16x16x32_bf16(A0, B0, z, 0, 0, 0);
        D = __builtin_amdgcn_mfma_f32_16x16x32_bf16(A1, B1, D, 0, 0, 0);
        #pragma unroll
        for (int g = 0; g < 4; g++) {
            int co = 16 * t + 4 * q + g;
            int idx = (b * Cc + co) * HW + hw;
            float xv = fl ? b2f(((const ushortT*)x)[idx]) : ((const float*)x)[idx];
            float res = xv + kba[idx] * ca1[b * Cc + co] + D[g] * ca2[b * Cc + co];
            if (fl) ((ushortT*)out)[idx] = f2b(res);
            else    ((float*)out)[idx] = res;
        }
    }
}

// ---------------- host launch ----------------
extern "C" void kernel_launch(void* const* d_in, const int* in_sizes, int n_in,
                              void* d_out, int out_size, void* d_ws, size_t ws_size,
                              hipStream_t stream) {
    float* ws_f = (float*)d_ws;

    float* xn    = ws_f + FXN;
    float* bufA  = ws_f + FA;     // t1 -> qkvr -> Sp
    float* bufB  = ws_f + FB;     // t2
    float* bufC  = ws_f + FC;     // x1g -> qkv
    float* bufD  = ws_f + FD;     // uf
    float* araw  = ws_f + FARAW;
    float* attn_t= ws_f + FATT;
    float* kba   = ws_f + FKBA;
    float* gap   = ws_f + FGAP;
    float* ca1   = ws_f + FCA1;
    float* ca2   = ws_f + FCA2;
    float* Smat  = ws_f + FS;
    float* wts   = ws_f + FW;
    ushortT* att_bf  = (ushortT*)(ws_f + FATTB);
    ushortT* Wt      = (ushortT*)(ws_f + FWT);
    ushortT* xnb     = (ushortT*)(ws_f + FXNB);
    ushortT* xmb     = (ushortT*)(ws_f + FXMB);
    ushortT* h_bf    = (ushortT*)(ws_f + FHBF);
    ushortT* mdta_bf = (ushortT*)(ws_f + FMDB);
    ushortT* Wpw     = (ushortT*)(ws_f + FWPW);
    ushortT* Wqk     = (ushortT*)(ws_f + FWQK);
    ushortT* Wkp     = (ushortT*)(ws_f + FWKP);
    ushortT* Wmp     = (ushortT*)(ws_f + FWMP);

    float* qkvr = bufA;
    float* qkv  = bufC;
    float* Sp   = bufA;
    const uint32_t* n1w_raw = (const uint32_t*)d_in[1];

    static const int wsizes[27] = {48,48,48,48,4608,864,4608,864,4608,432,24,384,32,
                                   1536,32,110592,3072,32,96,8,6912,1296,2304,2304,48,2304,48};
    static const int woffs[27] = {W_N1W,W_N1B,W_N2W,W_N2B,W_KDW1,W_KDW2,W_KC1A,W_KC1B,
                                  W_KPROJ,W_C2AW,W_C2AB,W_C2BW,W_C2BB,W_C211W,W_C211B,
                                  W_KW,W_KB,W_ATTG,W_GA1,W_TEMP,W_QKVW,W_QKVDW,W_MPROJ,
                                  W_CA1W,W_CA1B,W_CA2W,W_CA2B};
    ConvPack cp;
    for (int i = 0; i < 27; i++) {
        cp.src[i] = d_in[i + 1];
        cp.dstoff[i] = woffs[i];
        cp.n[i] = wsizes[i];
    }
    RawW rw;
    rw.kdw1 = d_in[5]; rw.kc1a = d_in[7]; rw.c211w = d_in[14]; rw.qkvw = d_in[21];
    rw.kproj = d_in[9]; rw.mproj = d_in[23]; rw.kw = d_in[16]; rw.kb = d_in[17];

    k_prep<<<dim3(64, 33), 256, 0, stream>>>(cp, rw, wts, Wt, Wpw, Wqk, Wkp, Wmp,
                                             d_in[0], gap, n1w_raw);
    k_ln<<<dim3(256), 64, 0, stream>>>(d_in[0], n1w_raw, wts, xn, xnb, xmb);
    k_pw1m<<<dim3(256), 256, 0, stream>>>(xnb, Wpw, wts, bufA, bufB, attn_t);
    k_dw<<<dim3(16, 216), 256, 0, stream>>>(bufA, bufB, xn, wts, bufC, bufD, araw);
    k_att<<<dim3(64), 256, 0, stream>>>(araw, attn_t, wts, att_bf);
    k_kba<<<dim3(64, 24), 256, 0, stream>>>(att_bf, bufD, bufC, Wt, wts, h_bf);
    k_kprojm<<<dim3(256), 256, 0, stream>>>(h_bf, Wkp, kba);
    k_qkvpwm<<<dim3(256), 256, 0, stream>>>(xmb, Wqk, qkvr);
    k_qkvdw<<<dim3(16, 144), 256, 0, stream>>>(qkvr, wts, qkv);
    k_smat1<<<dim3(32, 16), 256, 0, stream>>>(qkv, Sp);
    k_smat2<<<dim3(32), 64, 0, stream>>>(Sp, gap, wts, Smat, ca1, ca2);
    k_attout<<<dim3(64, 8), 256, 0, stream>>>(qkv, Smat, mdta_bf);
    k_finalm<<<dim3(256), 256, 0, stream>>>(d_in[0], n1w_raw, mdta_bf, Wmp,
                                            kba, ca1, ca2, d_out);
}